// Round 1
// baseline (130.146 us; speedup 1.0000x reference)
//
#include <hip/hip_runtime.h>

#define NT_ 24
#define K_ 64

// One 16-lane group per (b, t) row. Row = 128 contiguous f32:
//   [0..63]  = sim, [64..127] = ys (0.0/1.0).
// Lane j loads sim[j*4..j*4+3] and ys[j*4..j*4+3] as float4 (fully coalesced,
// 16 B/lane), computes 4 sigmoid terms, then a 4-step shfl_xor reduce over
// the 16-lane group; lane 0 writes z = sum + b2.
__global__ __launch_bounds__(256) void irv_kernel(
    const float* __restrict__ inputs,
    const float* __restrict__ V,
    const float* __restrict__ W,
    const float* __restrict__ b,
    const float* __restrict__ b2,
    float* __restrict__ out,
    int total_rows)
{
    const int tid = blockIdx.x * blockDim.x + threadIdx.x;
    const int row = tid >> 4;   // 16 lanes per row
    const int j   = tid & 15;
    if (row >= total_rows) return;

    // Uniform scalar params -> s_load via uniform kernel-arg pointers.
    const float W0  = W[0];
    const float W1  = W[1];
    const float bb  = b[0];
    const float bb2 = b2[0];
    const float V0  = V[0];
    const float dV  = V[1] - V0;   // v = V0 + y*dV  (exact for y in {0,1})

    const float* rowp = inputs + (size_t)row * (2 * K_);
    const float4 s4 = *reinterpret_cast<const float4*>(rowp + j * 4);
    const float4 y4 = *reinterpret_cast<const float4*>(rowp + K_ + j * 4);

    float sum = 0.0f;
    #pragma unroll
    for (int e = 0; e < 4; ++e) {
        const float sim  = (&s4.x)[e];          // compile-time index after unroll
        const float y    = (&y4.x)[e];
        const float rank = (float)(j * 4 + e + 1);
        const float s    = fmaf(W0, sim, fmaf(W1, rank, bb));
        // sigmoid via fast exp + hw rcp (v_exp_f32 / v_rcp_f32); ~1-2 ulp,
        // far below the 1.015 absmax threshold on a sum of 64 terms <= 1.
        const float en = __expf(-s);
        const float R  = __builtin_amdgcn_rcpf(1.0f + en);
        const float v  = fmaf(y, dV, V0);
        sum = fmaf(R, v, sum);
    }

    // Reduce across the 16-lane group.
    sum += __shfl_xor(sum, 1, 16);
    sum += __shfl_xor(sum, 2, 16);
    sum += __shfl_xor(sum, 4, 16);
    sum += __shfl_xor(sum, 8, 16);

    if (j == 0) out[row] = sum + bb2;
}

extern "C" void kernel_launch(void* const* d_in, const int* in_sizes, int n_in,
                              void* d_out, int out_size, void* d_ws, size_t ws_size,
                              hipStream_t stream) {
    const float* inputs = (const float*)d_in[0];
    const float* V      = (const float*)d_in[1];
    const float* W      = (const float*)d_in[2];
    const float* b      = (const float*)d_in[3];
    const float* b2     = (const float*)d_in[4];
    float* out = (float*)d_out;

    const int total_rows = out_size;              // B * NT
    const long long threads = (long long)total_rows * 16;
    const int block = 256;
    const int grid  = (int)((threads + block - 1) / block);

    irv_kernel<<<grid, block, 0, stream>>>(inputs, V, W, b, b2, out, total_rows);
}